// Round 14
// baseline (19.150 us; speedup 1.0000x reference)
//
#include <hip/hip_runtime.h>
#include <math.h>

#define AA 36
#define FWW 106
#define NTOT 122112        /* 32*106*36 */
#define BB 4
#define GG 64
#define STRIDE_PX 16
#define FBIG 3.402823466e+38f

constexpr int BLOCK = 512;                               // 8 waves
constexpr int NW    = BLOCK / 64;                        // 8
constexpr int BLOCKS_PER_B = (NTOT + BLOCK - 1) / BLOCK; // 239 (last block ragged)
constexpr int NBLK = BB * BLOCKS_PER_B;                  // 956

__device__ __forceinline__ float smooth_l1(float x) {
    float ax = fabsf(x);
    return (ax < 1.0f) ? 0.5f * ax * ax : ax - 0.5f;
}
__device__ __forceinline__ float frcp(float x) { return __builtin_amdgcn_rcpf(x); }

// DPP self-move: result = dpp(src) where valid, else old(=x) -> identity for min/max
#define DPP_SELF(x, ctrl, rm)                                                 \
    __int_as_float(__builtin_amdgcn_update_dpp(__float_as_int(x),             \
                   __float_as_int(x), ctrl, rm, 0xf, false))
// DPP zero-fill: invalid lanes contribute 0 (identity for sum)
#define DPP_ZERO(x, ctrl, rm)                                                 \
    __int_as_float(__builtin_amdgcn_update_dpp(0, __float_as_int(x),          \
                   ctrl, rm, 0xf, true))
#define RLANE_F(v, l) __int_as_float(__builtin_amdgcn_readlane(__float_as_int(v), (l)))

__device__ __forceinline__ float wave_sum64(float x) {   // total in lane 63
    x += DPP_ZERO(x, 0x111, 0xf);
    x += DPP_ZERO(x, 0x112, 0xf);
    x += DPP_ZERO(x, 0x114, 0xf);
    x += DPP_ZERO(x, 0x118, 0xf);
    x += DPP_ZERO(x, 0x142, 0xa);
    x += DPP_ZERO(x, 0x143, 0xc);
    return x;
}
__device__ __forceinline__ float wave_min64_bcast(float x) {  // uniform result
    x = fminf(x, DPP_SELF(x, 0x111, 0xf));
    x = fminf(x, DPP_SELF(x, 0x112, 0xf));
    x = fminf(x, DPP_SELF(x, 0x114, 0xf));
    x = fminf(x, DPP_SELF(x, 0x118, 0xf));
    x = fminf(x, DPP_SELF(x, 0x142, 0xa));
    x = fminf(x, DPP_SELF(x, 0x143, 0xc));
    return RLANE_F(x, 63);
}
__device__ __forceinline__ float wave_max64_bcast(float x) {  // uniform result
    x = fmaxf(x, DPP_SELF(x, 0x111, 0xf));
    x = fmaxf(x, DPP_SELF(x, 0x112, 0xf));
    x = fmaxf(x, DPP_SELF(x, 0x114, 0xf));
    x = fmaxf(x, DPP_SELF(x, 0x118, 0xf));
    x = fmaxf(x, DPP_SELF(x, 0x142, 0xa));
    x = fmaxf(x, DPP_SELF(x, 0x143, 0xc));
    return RLANE_F(x, 63);
}

__global__ __launch_bounds__(BLOCK) void rpn_loss_main(
    const float* __restrict__ cls,
    const float* __restrict__ bbox2d,
    const float* __restrict__ bbox3d,
    const float* __restrict__ anchors,
    const float* __restrict__ means,
    const float* __restrict__ stds,
    const float* __restrict__ gt_boxes,
    const float* __restrict__ gt3d,
    const int*   __restrict__ gt_labels,
    float4* __restrict__ part)
{
    __shared__ float4 s_red[NW];     // ONLY LDS in the kernel

    const int tid  = threadIdx.x;
    const int lane = tid & 63;
    const int wv   = tid >> 6;
    const int b    = blockIdx.x / BLOCKS_PER_B;            // block-uniform
    const int bpos = blockIdx.x % BLOCKS_PER_B;
    const int n0   = bpos * BLOCK;
    const int n    = n0 + tid;
    const bool valid = (n < NTOT);

    const float4* __restrict__ gtb = reinterpret_cast<const float4*>(gt_boxes) + b * GG;

    // ---- own cls row (issued first; exec-masked for ragged tail) ----
    const size_t row = (size_t)b * NTOT + n;
    float4 c = make_float4(0.f, 0.f, 0.f, 0.f);
    if (valid) c = reinterpret_cast<const float4*>(cls)[row];

    // ---- per-thread ROI from global anchors (1.3 KB, L1-hot) ----
    const int aidx  = n % AA;
    const int shift = n / AA;
    const float sx  = (float)((shift % FWW) * STRIDE_PX);
    const float sy  = (float)((shift / FWW) * STRIDE_PX);
    const float a0 = anchors[aidx * 9 + 0];
    const float a1 = anchors[aidx * 9 + 1];
    const float a2 = anchors[aidx * 9 + 2];
    const float a3 = anchors[aidx * 9 + 3];
    const float aw  = a2 - a0 + 1.0f;
    const float ah  = a3 - a1 + 1.0f;
    const float x1  = sx + a0;
    const float y1  = sy + a1;
    const float x2p = x1 + aw;
    const float y2p = y1 + ah;
    const float ar  = aw * ah;

    // ---- this lane's GT (1 KB coalesced, L1-hot across waves) ----
    const float4 gt   = gtb[lane];
    const float  gz1p = gt.z + 1.0f;
    const float  gw1p = gt.w + 1.0f;
    const float  ag   = (gz1p - gt.x) * (gw1p - gt.y);

    // ---- anchor aggregates via DPP (identical in every wave; no LDS/barrier) ----
    float e0 = FBIG, e1 = FBIG, e2 = -FBIG, e3 = -FBIG, ew = 0.f, eh = 0.f, eS = FBIG;
    if (lane < AA) {
        const float b0 = anchors[lane * 9 + 0];
        const float b1 = anchors[lane * 9 + 1];
        const float b2 = anchors[lane * 9 + 2];
        const float b3 = anchors[lane * 9 + 3];
        e0 = b0; e1 = b1; e2 = b2; e3 = b3;
        ew = b2 - b0 + 1.0f;
        eh = b3 - b1 + 1.0f;
        eS = ew * eh;
    }
    const float mnx = wave_min64_bcast(e0);
    const float mny = wave_min64_bcast(e1);
    const float mxx = wave_max64_bcast(e2);
    const float mxy = wave_max64_bcast(e3);
    const float mxw = wave_max64_bcast(ew) + 1.0f;   // +1 px rounding slack
    const float mxh = wave_max64_bcast(eh) + 1.0f;
    const float mnS = wave_min64_bcast(eS);

    // ---- block window(s): <=2 single-row x-spans ----
    const int nlast = (n0 + BLOCK - 1 < NTOT) ? (n0 + BLOCK - 1) : (NTOT - 1);
    const int s0  = n0 / AA,  s1  = nlast / AA;
    const int sy0 = s0 / FWW, sy1 = s1 / FWW;
    float fxA0, fxA1, fyA, fxB0, fxB1, fyB;
    if (sy0 == sy1) {
        fxA0 = (float)((s0 % FWW) * STRIDE_PX); fxA1 = (float)((s1 % FWW) * STRIDE_PX);
        fyA  = (float)(sy0 * STRIDE_PX);
        fxB0 = fxA0; fxB1 = fxA1; fyB = fyA;
    } else {
        fxA0 = (float)((s0 % FWW) * STRIDE_PX); fxA1 = (float)((FWW - 1) * STRIDE_PX);
        fyA  = (float)(sy0 * STRIDE_PX);
        fxB0 = 0.0f;                            fxB1 = (float)((s1 % FWW) * STRIDE_PX);
        fyB  = (float)(sy1 * STRIDE_PX);
    }

    // ---- aggregate fg-feasibility test (sound UB): identical mask in every wave ----
    // window A
    float iwA = fminf(fxA1 + mxx + 1.0f, gz1p) - fmaxf(fxA0 + mnx, gt.x);
    iwA = fmaxf(fminf(iwA, mxw), 0.0f);
    float ihA = fminf(fyA + mxy + 1.0f, gw1p) - fmaxf(fyA + mny, gt.y);
    ihA = fmaxf(fminf(ihA, mxh), 0.0f);
    bool pass = (3.0f * iwA * ihA >= mnS + ag);
    // window B
    float iwB = fminf(fxB1 + mxx + 1.0f, gz1p) - fmaxf(fxB0 + mnx, gt.x);
    iwB = fmaxf(fminf(iwB, mxw), 0.0f);
    float ihB = fminf(fyB + mxy + 1.0f, gw1p) - fmaxf(fyB + mny, gt.y);
    ihB = fmaxf(fminf(ihB, mxh), 0.0f);
    pass = pass || (3.0f * iwB * ihB >= mnS + ag);

    unsigned long long m = __ballot(pass);     // wave-uniform survivor mask

    // ---- CE logsumexp (GT-independent) ----
    const float lse = __logf(__expf(c.x) + __expf(c.y) + __expf(c.z) + __expf(c.w));

    // ---- argmax over survivors: readlane broadcasts, zero LDS, first-max order ----
    float bi = 0.0f, bS = 1.0f;
    int   bk = 0;
    while (m) {
        const int g = (int)__builtin_ctzll(m);
        m &= (m - 1ull);
        const float gxs = RLANE_F(gt.x,  g);
        const float gys = RLANE_F(gt.y,  g);
        const float gzs = RLANE_F(gz1p,  g);
        const float gws = RLANE_F(gw1p,  g);
        const float ags = RLANE_F(ag,    g);
        const float iw = fminf(x2p, gzs) - fmaxf(x1, gxs);
        const float ih = fmaxf(fminf(y2p, gws) - fmaxf(y1, gys), 0.0f);
        const float inter = iw * ih;              // <=0 can never win (bi>=0)
        const float S     = ar + ags;
        const bool upd = inter * bS > bi * S;     // exact cross-mult, first-max
        bi = upd ? inter : bi;
        bS = upd ? S     : bS;
        bk = upd ? g     : bk;
    }
    const bool fg = valid && (3.0f * bi >= bS);   // exact: best_iou >= 0.5

    int label = 0;
    if (fg) label = gt_labels[b * GG + bk];
    const float csel = (label == 0) ? c.x : (label == 1) ? c.y :
                       (label == 2) ? c.z : c.w;
    const float ce = valid ? (lse - csel) : 0.0f;

    // ---- bbox losses (fg only; rare, exec-masked) ----
    float l23 = 0.0f;
    if (fg) {
        const float cx  = x1 + 0.5f * aw;
        const float cy  = y1 + 0.5f * ah;
        const float rw  = frcp(aw);
        const float rh  = frcp(ah);
        const float4 gq = gtb[bk];                // divergent, rare, L1-hot
        const float gw_ = gq.z - gq.x + 1.0f;
        const float gh_ = gq.w - gq.y + 1.0f;
        const float gcx = gq.x + 0.5f * gw_;
        const float gcy = gq.y + 0.5f * gh_;
        float t2[4];
        t2[0] = (gcx - cx) * rw;
        t2[1] = (gcy - cy) * rh;
        t2[2] = __logf(gw_ * rw);
        t2[3] = __logf(gh_ * rh);
        const float4 p2 = reinterpret_cast<const float4*>(bbox2d)[row];
        const float p2a[4] = {p2.x, p2.y, p2.z, p2.w};
        #pragma unroll
        for (int k = 0; k < 4; ++k)
            l23 += smooth_l1(p2a[k] - (t2[k] - means[k]) * frcp(stds[k]));

        const float an4 = anchors[aidx * 9 + 4];
        const float an5 = anchors[aidx * 9 + 5];
        const float an6 = anchors[aidx * 9 + 6];
        const float an7 = anchors[aidx * 9 + 7];
        const float an8 = anchors[aidx * 9 + 8];
        const float* g3 = gt3d + ((size_t)b * GG + bk) * 7;
        float t3[7];
        t3[0] = (g3[0] - cx) * rw;
        t3[1] = (g3[1] - cy) * rh;
        t3[2] = g3[2] - an4;
        t3[3] = __logf(g3[3] * frcp(an5));
        t3[4] = __logf(g3[4] * frcp(an6));
        t3[5] = __logf(g3[5] * frcp(an7));
        t3[6] = g3[6] - an8;
        const float* p3 = bbox3d + row * 7;
        #pragma unroll
        for (int k = 0; k < 7; ++k)
            l23 += smooth_l1(p3[k] - (t3[k] - means[4 + k]) * frcp(stds[4 + k]));
    }

    // ---- reduction: DPP wave sums (lane 63), nfg via ballot; ONE barrier ----
    const float vce = wave_sum64(ce);
    const float vl  = wave_sum64(l23);
    const float nfgw = (float)__popcll(__ballot(fg));
    if (lane == 63) s_red[wv] = make_float4(vce, vl, nfgw, 0.f);
    __syncthreads();
    if (tid < NW) {
        float4 p = s_red[tid];
        #pragma unroll
        for (int mm = 1; mm < NW; mm <<= 1) {
            p.x += __shfl_xor(p.x, mm, 64);
            p.y += __shfl_xor(p.y, mm, 64);
            p.z += __shfl_xor(p.z, mm, 64);
        }
        if (tid == 0) part[blockIdx.x] = p;
    }
}

__global__ __launch_bounds__(256) void rpn_loss_fin(
    const float4* __restrict__ part, float* __restrict__ out)
{
    __shared__ float4 sh[4];
    float ce = 0.f, l23 = 0.f, nfg = 0.f;
    for (int i = threadIdx.x; i < NBLK; i += 256) {
        const float4 p = part[i];
        ce += p.x; l23 += p.y; nfg += p.z;
    }
    ce  = wave_sum64(ce);
    l23 = wave_sum64(l23);
    nfg = wave_sum64(nfg);
    const int lane = threadIdx.x & 63;
    const int wv   = threadIdx.x >> 6;
    if (lane == 63) sh[wv] = make_float4(ce, l23, nfg, 0.f);
    __syncthreads();
    if (threadIdx.x == 0) {
        float a = 0.f, l = 0.f, g = 0.f;
        #pragma unroll
        for (int i = 0; i < 4; ++i) { a += sh[i].x; l += sh[i].y; g += sh[i].z; }
        out[0] = a / (float)((size_t)BB * NTOT) + l / fmaxf(g, 1.0f);
    }
}

extern "C" void kernel_launch(void* const* d_in, const int* in_sizes, int n_in,
                              void* d_out, int out_size, void* d_ws, size_t ws_size,
                              hipStream_t stream) {
    const float* cls     = (const float*)d_in[0];
    // d_in[1] = prob (unused by the loss)
    const float* bbox2d  = (const float*)d_in[2];
    const float* bbox3d  = (const float*)d_in[3];
    // d_in[4] = rois — reconstructed from anchors + linear index
    const float* anchors = (const float*)d_in[5];
    const float* means   = (const float*)d_in[6];
    const float* stds    = (const float*)d_in[7];
    const float* gtb     = (const float*)d_in[8];
    const float* gt3     = (const float*)d_in[9];
    const int*   glbl    = (const int*)d_in[10];
    float4* part = (float4*)d_ws;      // NBLK float4 partials, fully overwritten
    float*  out  = (float*)d_out;

    rpn_loss_main<<<dim3(NBLK), BLOCK, 0, stream>>>(cls, bbox2d, bbox3d, anchors,
                                                    means, stds, gtb, gt3, glbl, part);
    rpn_loss_fin<<<1, 256, 0, stream>>>(part, out);
}

// Round 15
// 16.016 us; speedup vs baseline: 1.1956x; 1.1956x over previous
//
#include <hip/hip_runtime.h>
#include <math.h>

#define AA 36
#define FWW 106
#define NTOT 122112        /* 32*106*36 */
#define BB 4
#define GG 64
#define STRIDE_PX 16

constexpr int BLOCK = 512;                               // 8 waves
constexpr int NW    = BLOCK / 64;                        // 8
constexpr int BLOCKS_PER_B = (NTOT + BLOCK - 1) / BLOCK; // 239 (last block ragged)
constexpr int NBLK = BB * BLOCKS_PER_B;                  // 956

__device__ __forceinline__ float smooth_l1(float x) {
    float ax = fabsf(x);
    return (ax < 1.0f) ? 0.5f * ax * ax : ax - 0.5f;
}
__device__ __forceinline__ float frcp(float x) { return __builtin_amdgcn_rcpf(x); }

#define DPP_ZERO(x, ctrl, rm)                                                 \
    __int_as_float(__builtin_amdgcn_update_dpp(0, __float_as_int(x),          \
                   ctrl, rm, 0xf, true))
#define RLANE_F(v, l) __int_as_float(__builtin_amdgcn_readlane(__float_as_int(v), (l)))

__device__ __forceinline__ float wave_sum64(float x) {   // total in lane 63
    x += DPP_ZERO(x, 0x111, 0xf);
    x += DPP_ZERO(x, 0x112, 0xf);
    x += DPP_ZERO(x, 0x114, 0xf);
    x += DPP_ZERO(x, 0x118, 0xf);
    x += DPP_ZERO(x, 0x142, 0xa);
    x += DPP_ZERO(x, 0x143, 0xc);
    return x;
}

__global__ __launch_bounds__(BLOCK) void rpn_loss_main(
    const float* __restrict__ cls,
    const float* __restrict__ bbox2d,
    const float* __restrict__ bbox3d,
    const float* __restrict__ anchors,
    const float* __restrict__ means,
    const float* __restrict__ stds,
    const float* __restrict__ gt_boxes,
    const float* __restrict__ gt3d,
    const int*   __restrict__ gt_labels,
    float4* __restrict__ part)
{
    __shared__ float4 s_gt4[GG];            // compacted {gx1, gy1, gx2+1, gy2+1}
    __shared__ float  s_gS[GG];             // compacted area_g
    __shared__ int    s_gidx[GG];           // compacted -> original g
    __shared__ float4 s_anch4[AA];          // {ax1, ay1, aw, ah}
    __shared__ float  s_anch[AA * 13];      // raw 9 fields (stride 13)
    __shared__ unsigned long long s_bal[NW];
    __shared__ float4 s_red[NW];
    __shared__ int    s_K;

    const int tid  = threadIdx.x;
    const int lane = tid & 63;
    const int wv   = tid >> 6;
    const int wvu  = __builtin_amdgcn_readfirstlane(wv);   // force wave-uniform
    const int b    = blockIdx.x / BLOCKS_PER_B;            // block-uniform
    const int bpos = blockIdx.x % BLOCKS_PER_B;
    const int n0   = bpos * BLOCK;
    const int n    = n0 + tid;
    const bool valid = (n < NTOT);

    const float4* __restrict__ gtb = reinterpret_cast<const float4*>(gt_boxes) + b * GG;

    // ---- early: own cls row (exec-masked for the ragged tail) ----
    const size_t row = (size_t)b * NTOT + n;
    float4 c = make_float4(0.f, 0.f, 0.f, 0.f);
    if (valid) c = reinterpret_cast<const float4*>(cls)[row];

    // ---- stage anchors (threads 0..35, concurrent with prune) ----
    if (tid < AA) {
        float a[9];
        #pragma unroll
        for (int k = 0; k < 9; ++k) a[k] = anchors[tid * 9 + k];
        #pragma unroll
        for (int k = 0; k < 9; ++k) s_anch[tid * 13 + k] = a[k];
        s_anch4[tid] = make_float4(a[0], a[1], a[2] - a[0] + 1.0f, a[3] - a[1] + 1.0f);
    }

    // ---- block window(s): <=2 single-row x-spans ----
    const int nlast = (n0 + BLOCK - 1 < NTOT) ? (n0 + BLOCK - 1) : (NTOT - 1);
    const int s0  = n0 / AA,  s1  = nlast / AA;
    const int sy0 = s0 / FWW, sy1 = s1 / FWW;
    float fxA0, fxA1, fyA, fxB0, fxB1, fyB;
    if (sy0 == sy1) {
        fxA0 = (float)((s0 % FWW) * STRIDE_PX); fxA1 = (float)((s1 % FWW) * STRIDE_PX);
        fyA  = (float)(sy0 * STRIDE_PX);
        fxB0 = fxA0; fxB1 = fxA1; fyB = fyA;
    } else {
        fxA0 = (float)((s0 % FWW) * STRIDE_PX); fxA1 = (float)((FWW - 1) * STRIDE_PX);
        fyA  = (float)(sy0 * STRIDE_PX);
        fxB0 = 0.0f;                            fxB1 = (float)((s1 % FWW) * STRIDE_PX);
        fyB  = (float)(sy1 * STRIDE_PX);
    }

    // this lane's GT (4 KB, L2-warm)
    const float4 gt   = gtb[lane];
    const float  gz1p = gt.z + 1.0f;
    const float  gw1p = gt.w + 1.0f;
    const float  ag   = (gz1p - gt.x) * (gw1p - gt.y);

    // ---- parallel fg-feasibility prune: wave wv tests anchors {wvu, wvu+8, ...} ----
    bool pass = false;
    for (int a = wvu; a < AA; a += NW) {      // wave-uniform a -> scalar loads
        const float ax1 = anchors[a * 9 + 0];
        const float ay1 = anchors[a * 9 + 1];
        const float aw  = anchors[a * 9 + 2] - ax1 + 1.0f;
        const float ah  = anchors[a * 9 + 3] - ay1 + 1.0f;
        const float thr = aw * ah + ag;
        float iwA = fminf(fxA1 + ax1 + aw, gz1p) - fmaxf(fxA0 + ax1, gt.x);
        float ihA = fminf(fyA  + ay1 + ah, gw1p) - fmaxf(fyA  + ay1, gt.y);
        iwA = fmaxf(fminf(iwA, aw), 0.0f);
        ihA = fmaxf(fminf(ihA, ah), 0.0f);
        pass |= (3.0f * iwA * ihA >= thr);
        float iwB = fminf(fxB1 + ax1 + aw, gz1p) - fmaxf(fxB0 + ax1, gt.x);
        float ihB = fminf(fyB  + ay1 + ah, gw1p) - fmaxf(fyB  + ay1, gt.y);
        iwB = fmaxf(fminf(iwB, aw), 0.0f);
        ihB = fmaxf(fminf(ihB, ah), 0.0f);
        pass |= (3.0f * iwB * ihB >= thr);
    }
    const unsigned long long wmask = __ballot(pass);
    if (lane == 0) s_bal[wv] = wmask;
    __syncthreads();                                   // B1

    // ---- wave 0: OR ballots, stable compaction ----
    if (wv == 0) {
        unsigned long long mask = 0ull;
        #pragma unroll
        for (int j = 0; j < NW; ++j) mask |= s_bal[j];
        if ((mask >> lane) & 1ull) {
            const int pos = __popcll(mask & ((1ull << lane) - 1ull));
            s_gt4[pos]  = make_float4(gt.x, gt.y, gz1p, gw1p);
            s_gS[pos]   = ag;
            s_gidx[pos] = lane;
        }
        if (lane == 0) s_K = __popcll(mask);
    }
    __syncthreads();                                   // B2

    // ---- survivor self-read: lane l holds survivor l (2 LDS reads TOTAL) ----
    const float4 sv4 = s_gt4[lane];          // garbage for lane >= K: never selected
    const float  svS = s_gS[lane];

    // ---- per-thread ROI ----
    const int aidx  = n % AA;
    const int shift = n / AA;
    const float sx  = (float)((shift % FWW) * STRIDE_PX);
    const float sy  = (float)((shift / FWW) * STRIDE_PX);
    const float4 A4 = s_anch4[aidx];
    const float aw  = A4.z;
    const float ah  = A4.w;
    const float x1  = sx + A4.x;
    const float y1  = sy + A4.y;
    const float x2p = x1 + aw;
    const float y2p = y1 + ah;
    const float ar  = aw * ah;

    // lse transcendentals overlap the sv4/svS LDS latency
    const float lse = __logf(__expf(c.x) + __expf(c.y) + __expf(c.z) + __expf(c.w));

    // ---- argmax over survivors: readlane broadcasts, ZERO in-loop memory ----
    const int K = s_K;
    float bi = 0.0f, bS = 1.0f;
    int   bk = 0;
    for (int k = 0; k < K; ++k) {            // k wave-uniform -> SGPR lane select
        const float gxs = RLANE_F(sv4.x, k);
        const float gys = RLANE_F(sv4.y, k);
        const float gzs = RLANE_F(sv4.z, k);
        const float gws = RLANE_F(sv4.w, k);
        const float ags = RLANE_F(svS,   k);
        const float iw = fminf(x2p, gzs) - fmaxf(x1, gxs);
        const float ih = fmaxf(fminf(y2p, gws) - fmaxf(y1, gys), 0.0f);
        const float inter = iw * ih;              // <=0 can never win (bi>=0)
        const float S     = ar + ags;
        const bool upd = inter * bS > bi * S;     // exact cross-mult, first-max
        bi = upd ? inter : bi;
        bS = upd ? S     : bS;
        bk = upd ? k     : bk;
    }
    const bool fg = valid && (3.0f * bi >= bS);   // exact: best_iou >= 0.5

    int label = 0;
    if (fg) label = gt_labels[b * GG + s_gidx[bk]];
    const float csel = (label == 0) ? c.x : (label == 1) ? c.y :
                       (label == 2) ? c.z : c.w;
    const float ce = valid ? (lse - csel) : 0.0f;

    // ---- bbox losses (fg only; rare) ----
    float l23 = 0.0f;
    if (fg) {
        const float cx  = x1 + 0.5f * aw;
        const float cy  = y1 + 0.5f * ah;
        const float rw  = frcp(aw);
        const float rh  = frcp(ah);
        const float4 gq = s_gt4[bk];            // {gx1, gy1, gx2+1, gy2+1}
        const float gw_ = gq.z - gq.x;
        const float gh_ = gq.w - gq.y;
        const float gcx = gq.x + 0.5f * gw_;
        const float gcy = gq.y + 0.5f * gh_;
        float t2[4];
        t2[0] = (gcx - cx) * rw;
        t2[1] = (gcy - cy) * rh;
        t2[2] = __logf(gw_ * rw);
        t2[3] = __logf(gh_ * rh);
        const float4 p2 = reinterpret_cast<const float4*>(bbox2d)[row];
        const float p2a[4] = {p2.x, p2.y, p2.z, p2.w};
        #pragma unroll
        for (int k = 0; k < 4; ++k)
            l23 += smooth_l1(p2a[k] - (t2[k] - means[k]) * frcp(stds[k]));

        const float* an = &s_anch[aidx * 13];
        const float* g3 = gt3d + ((size_t)b * GG + s_gidx[bk]) * 7;
        float t3[7];
        t3[0] = (g3[0] - cx) * rw;
        t3[1] = (g3[1] - cy) * rh;
        t3[2] = g3[2] - an[4];
        t3[3] = __logf(g3[3] * frcp(an[5]));
        t3[4] = __logf(g3[4] * frcp(an[6]));
        t3[5] = __logf(g3[5] * frcp(an[7]));
        t3[6] = g3[6] - an[8];
        const float* p3 = bbox3d + row * 7;
        #pragma unroll
        for (int k = 0; k < 7; ++k)
            l23 += smooth_l1(p3[k] - (t3[k] - means[4 + k]) * frcp(stds[4 + k]));
    }

    // ---- reduction: DPP wave sums (lane 63), nfg via ballot ----
    const float vce = wave_sum64(ce);
    const float vl  = wave_sum64(l23);
    const float nfgw = (float)__popcll(__ballot(fg));
    if (lane == 63) s_red[wv] = make_float4(vce, vl, nfgw, 0.f);
    __syncthreads();                                   // B3
    if (tid < NW) {
        float4 p = s_red[tid];
        #pragma unroll
        for (int m = 1; m < NW; m <<= 1) {
            p.x += __shfl_xor(p.x, m, 64);
            p.y += __shfl_xor(p.y, m, 64);
            p.z += __shfl_xor(p.z, m, 64);
        }
        if (tid == 0) part[blockIdx.x] = p;
    }
}

__global__ __launch_bounds__(256) void rpn_loss_fin(
    const float4* __restrict__ part, float* __restrict__ out)
{
    __shared__ float4 sh[4];
    float ce = 0.f, l23 = 0.f, nfg = 0.f;
    for (int i = threadIdx.x; i < NBLK; i += 256) {
        const float4 p = part[i];
        ce += p.x; l23 += p.y; nfg += p.z;
    }
    ce  = wave_sum64(ce);
    l23 = wave_sum64(l23);
    nfg = wave_sum64(nfg);
    const int lane = threadIdx.x & 63;
    const int wv   = threadIdx.x >> 6;
    if (lane == 63) sh[wv] = make_float4(ce, l23, nfg, 0.f);
    __syncthreads();
    if (threadIdx.x == 0) {
        float a = 0.f, l = 0.f, g = 0.f;
        #pragma unroll
        for (int i = 0; i < 4; ++i) { a += sh[i].x; l += sh[i].y; g += sh[i].z; }
        out[0] = a / (float)((size_t)BB * NTOT) + l / fmaxf(g, 1.0f);
    }
}

extern "C" void kernel_launch(void* const* d_in, const int* in_sizes, int n_in,
                              void* d_out, int out_size, void* d_ws, size_t ws_size,
                              hipStream_t stream) {
    const float* cls     = (const float*)d_in[0];
    // d_in[1] = prob (unused by the loss)
    const float* bbox2d  = (const float*)d_in[2];
    const float* bbox3d  = (const float*)d_in[3];
    // d_in[4] = rois — reconstructed from anchors + linear index
    const float* anchors = (const float*)d_in[5];
    const float* means   = (const float*)d_in[6];
    const float* stds    = (const float*)d_in[7];
    const float* gtb     = (const float*)d_in[8];
    const float* gt3     = (const float*)d_in[9];
    const int*   glbl    = (const int*)d_in[10];
    float4* part = (float4*)d_ws;      // NBLK float4 partials, fully overwritten
    float*  out  = (float*)d_out;

    rpn_loss_main<<<dim3(NBLK), BLOCK, 0, stream>>>(cls, bbox2d, bbox3d, anchors,
                                                    means, stds, gtb, gt3, glbl, part);
    rpn_loss_fin<<<1, 256, 0, stream>>>(part, out);
}